// Round 1
// baseline (20505.841 us; speedup 1.0000x reference)
//
#include <hip/hip_runtime.h>

#define T_LEN 2048
#define BATCH 128
#define HID   256
#define G4    1024
#define EMBD  128
#define VOCAB 128
#define OUTC  2
#define BSUB  16
#define NCHAIN 8
#define CHK   128          // x chunk length staged in LDS
#define HS    264          // padded hidden stride (bf16 elems): 528B rows -> 2-way bank alias only

typedef __bf16 bf16x8 __attribute__((ext_vector_type(8)));
typedef float  f32x4  __attribute__((ext_vector_type(4)));

// P[v][c] = sum_e emb[v,e]*W_ih[c,e] + b_ih[c] + b_hh[c]   (512 KB, device global scratch)
__device__ float Pbuf[VOCAB * G4];

__global__ void build_P(const float* __restrict__ emb, const float* __restrict__ W_ih,
                        const float* __restrict__ b_ih, const float* __restrict__ b_hh) {
    // grid 512 x 256: 4 blocks per vocab row
    const int v = blockIdx.x >> 2;
    const int c = ((blockIdx.x & 3) << 8) + threadIdx.x;
    __shared__ float es[EMBD];
    if (threadIdx.x < EMBD) es[threadIdx.x] = emb[v * EMBD + threadIdx.x];
    __syncthreads();
    const float* wr = W_ih + c * EMBD;
    float acc = 0.f;
    #pragma unroll 8
    for (int e = 0; e < EMBD; ++e) acc += es[e] * wr[e];
    Pbuf[v * G4 + c] = acc + b_ih[c] + b_hh[c];
}

__device__ __forceinline__ float sig_f(float v) {
    return 1.f / (1.f + __expf(-v));
}
__device__ __forceinline__ float tanh_f(float v) {
    // safe at +-inf: exp->inf gives 1, exp->0 gives -1
    float e = __expf(2.f * v);
    return 1.f - 2.f / (e + 1.f);
}

// one workgroup (1024 thr, 16 waves) = one chain of 16 batch rows, whole T loop on one CU.
__launch_bounds__(1024)
__global__ void lstm_chain(const int* __restrict__ x, const float* __restrict__ W_hh,
                           const float* __restrict__ fc_W, const float* __restrict__ fc_b,
                           float* __restrict__ out) {
    __shared__ alignas(16) __bf16 hbuf[2][BSUB * HS];   // h ping-pong, [batch][hid] bf16
    __shared__ int   xch[BSUB * CHK];                   // x indices chunk
    __shared__ float hfin[BSUB * HID];                  // final h (f32) for FC

    const int tid  = threadIdx.x;
    const int w    = tid >> 6;        // wave 0..15: owns hidden units [16w,16w+16)
    const int lane = tid & 63;
    const int l15  = lane & 15;
    const int quad = lane >> 4;
    const int bbase = blockIdx.x * BSUB;
    const int colb  = (w << 4) + l15; // hidden unit / gate column offset within each gate block

    // --- persistent B fragments: W_hh^T in MFMA B layout, bf16, 128 VGPRs/wave ---
    // B[k = kt*32 + quad*8 + j][n = gi*256 + colb] = W_hh[n][k]
    bf16x8 Bf[4][8];
    #pragma unroll
    for (int gi = 0; gi < 4; ++gi) {
        const float* wrow = W_hh + (gi * HID + colb) * HID;
        #pragma unroll
        for (int kt = 0; kt < 8; ++kt) {
            const float* wp = wrow + kt * 32 + quad * 8;
            bf16x8 b;
            #pragma unroll
            for (int j = 0; j < 8; ++j) b[j] = (__bf16)wp[j];
            Bf[gi][kt] = b;
        }
    }

    // zero h ping-pong buffers (h0 = 0)
    for (int i = tid; i < 2 * BSUB * HS; i += 1024) ((__bf16*)hbuf)[i] = (__bf16)0.f;

    float cst[4];                    // cell state: rows quad*4+u, hidden unit colb
    #pragma unroll
    for (int u = 0; u < 4; ++u) cst[u] = 0.f;

    float xg[16];                    // prefetched xg, [gi][u]

    __syncthreads();

    #pragma unroll 1
    for (int t = 0; t < T_LEN; ++t) {
        const int tt = t & (CHK - 1);
        if (tt == 0) {
            // refill x chunk (prev step's barrier already protects xch)
            #pragma unroll
            for (int i = tid; i < BSUB * CHK; i += 1024) {
                const int bi = i >> 7, tj = i & (CHK - 1);
                xch[i] = x[(bbase + bi) * T_LEN + t + tj];
            }
            __syncthreads();
            // no prefetch was possible across the chunk boundary: load xg now
            #pragma unroll
            for (int u = 0; u < 4; ++u) {
                const int xv = xch[(quad * 4 + u) * CHK + tt];
                #pragma unroll
                for (int gi = 0; gi < 4; ++gi)
                    xg[gi * 4 + u] = Pbuf[xv * G4 + gi * HID + colb];
            }
        }

        // A fragments: h_t from LDS, A[m = l15][k = kt*32 + quad*8 + j]
        const __bf16* hb = &hbuf[t & 1][0];
        bf16x8 a[8];
        #pragma unroll
        for (int kt = 0; kt < 8; ++kt)
            a[kt] = *(const bf16x8*)(hb + l15 * HS + kt * 32 + quad * 8);

        // init accumulators from xg (C layout: row = quad*4+u, col = gi*256+colb)
        f32x4 acc[4];
        #pragma unroll
        for (int gi = 0; gi < 4; ++gi) {
            f32x4 v;
            v[0] = xg[gi * 4 + 0]; v[1] = xg[gi * 4 + 1];
            v[2] = xg[gi * 4 + 2]; v[3] = xg[gi * 4 + 3];
            acc[gi] = v;
        }

        // prefetch xg for t+1 (hidden under the MFMAs); skipped at chunk boundary
        if (tt != CHK - 1) {
            #pragma unroll
            for (int u = 0; u < 4; ++u) {
                const int xv = xch[(quad * 4 + u) * CHK + tt + 1];
                #pragma unroll
                for (int gi = 0; gi < 4; ++gi)
                    xg[gi * 4 + u] = Pbuf[xv * G4 + gi * HID + colb];
            }
        }

        // 32 MFMAs: 4 independent K-chains (i,f,g,o)
        #pragma unroll
        for (int kt = 0; kt < 8; ++kt) {
            #pragma unroll
            for (int gi = 0; gi < 4; ++gi)
                acc[gi] = __builtin_amdgcn_mfma_f32_16x16x32_bf16(a[kt], Bf[gi][kt], acc[gi], 0, 0, 0);
        }

        // gate math + state update; write h_{t+1} (bf16) to the other buffer
        __bf16* hn = &hbuf[(t + 1) & 1][0];
        float hv[4];
        #pragma unroll
        for (int u = 0; u < 4; ++u) {
            const float is = sig_f(acc[0][u]);
            const float fs = sig_f(acc[1][u]);
            const float gt = tanh_f(acc[2][u]);
            const float os = sig_f(acc[3][u]);
            cst[u] = fs * cst[u] + is * gt;
            const float h = os * tanh_f(cst[u]);
            hv[u] = h;
            hn[(quad * 4 + u) * HS + colb] = (__bf16)h;
        }
        if (t == T_LEN - 1) {
            #pragma unroll
            for (int u = 0; u < 4; ++u)
                hfin[(quad * 4 + u) * HID + colb] = hv[u];
        }
        __syncthreads();
    }

    // final FC: logits[b,o] = hT[b,:] . fc_W[o,:] + fc_b[o]   (tiny, 32 threads)
    if (tid < BSUB * OUTC) {
        const int b = tid >> 1, o = tid & 1;
        float s = fc_b[o];
        #pragma unroll 8
        for (int j = 0; j < HID; ++j) s += hfin[b * HID + j] * fc_W[o * HID + j];
        out[(bbase + b) * OUTC + o] = s;
    }
}

extern "C" void kernel_launch(void* const* d_in, const int* in_sizes, int n_in,
                              void* d_out, int out_size, void* d_ws, size_t ws_size,
                              hipStream_t stream) {
    const int*   x    = (const int*)  d_in[0];
    const float* emb  = (const float*)d_in[1];
    const float* W_ih = (const float*)d_in[2];
    const float* W_hh = (const float*)d_in[3];
    const float* b_ih = (const float*)d_in[4];
    const float* b_hh = (const float*)d_in[5];
    const float* fc_W = (const float*)d_in[6];
    const float* fc_b = (const float*)d_in[7];
    float* out = (float*)d_out;

    build_P<<<dim3(VOCAB * 4), dim3(256), 0, stream>>>(emb, W_ih, b_ih, b_hh);
    lstm_chain<<<dim3(NCHAIN), dim3(1024), 0, stream>>>(x, W_hh, fc_W, fc_b, out);
}